// Round 4
// baseline (225.019 us; speedup 1.0000x reference)
//
#include <hip/hip_runtime.h>

// Problem constants (from reference): B=256, NSEL=60000, NVERTS=100000, F=3
#define B_C     256
#define NSEL_C  60000
#define NV_C    100000
#define SCAN_T  1024
#define NB1     ((NV_C + SCAN_T - 1) / SCAN_T)   // 98 scan blocks
#define NGRP    (NV_C / 4)                       // 25000 groups of 4 vertices
#define NBLK_G  ((NGRP + 255) / 256)             // 98 group-blocks per batch
#define NXCD    8

typedef float f32x4   __attribute__((ext_vector_type(4)));
typedef float f32x4_u __attribute__((ext_vector_type(4), aligned(4)));
typedef int   i32x4   __attribute__((ext_vector_type(4)));

// ---------------- CSR build ----------------

__global__ void zero_counts_k(int* __restrict__ counts) {
    int i = blockIdx.x * blockDim.x + threadIdx.x;
    if (i < NV_C) counts[i] = 0;
}

__global__ void hist_k(const int* __restrict__ vs, int* __restrict__ counts) {
    int j = blockIdx.x * blockDim.x + threadIdx.x;
    if (j < NSEL_C) atomicAdd(&counts[vs[j]], 1);
}

__global__ __launch_bounds__(SCAN_T) void scan1_k(const int* __restrict__ counts,
                                                  int* __restrict__ partial,
                                                  int* __restrict__ blockSums) {
    __shared__ int sm[SCAN_T];
    int tid = threadIdx.x;
    int i = blockIdx.x * SCAN_T + tid;
    int v = (i < NV_C) ? counts[i] : 0;
    int val = v;
    sm[tid] = val;
    __syncthreads();
    for (int off = 1; off < SCAN_T; off <<= 1) {
        int t = (tid >= off) ? sm[tid - off] : 0;
        __syncthreads();
        val += t;
        sm[tid] = val;
        __syncthreads();
    }
    if (i < NV_C) partial[i] = val - v;           // exclusive
    if (tid == SCAN_T - 1) blockSums[blockIdx.x] = val;
}

__global__ void scan2_k(const int* __restrict__ blockSums, int* __restrict__ blockOff) {
    if (blockIdx.x == 0 && threadIdx.x == 0) {
        int run = 0;
        for (int b = 0; b < NB1; ++b) { blockOff[b] = run; run += blockSums[b]; }
    }
}

__global__ void scan3_k(const int* __restrict__ partial, const int* __restrict__ blockOff,
                        int* __restrict__ offsets, int* __restrict__ cursor) {
    int i = blockIdx.x * blockDim.x + threadIdx.x;
    if (i < NV_C) {
        int o = partial[i] + blockOff[i / SCAN_T];
        offsets[i] = o;
        cursor[i]  = o;
    }
    if (i == 0) offsets[NV_C] = NSEL_C;
}

// list[] stores 3*j (float element offset into the batch slice).
__global__ void fill_k(const int* __restrict__ vs, int* __restrict__ cursor,
                       int* __restrict__ list) {
    int j = blockIdx.x * blockDim.x + threadIdx.x;
    if (j < NSEL_C) {
        int v = vs[j];
        int pos = atomicAdd(&cursor[v], 1);
        list[pos] = 3 * j;
    }
}

// ---------------- gather (the heavy kernel) ----------------
// 4 vertices per thread, combined loop with predicated accumulation.
// - x row read: ONE clamped dwordx4 (4B-aligned) instead of dwordx2+dword;
//   clamp to 3*NSEL-4 and shift-select handles the 16B overrun on the very
//   last row. Halves divergent VMEM instructions on the dependent chain.
// - offsets: one aligned int4 load + one scalar (2 VMEM instead of 5).
// - stores: plain (L2 write-combining) f32x4 x3 — NT caused partial-line
//   write amplification (375 MB vs 300 MB) because the 3 stores' 48B-stride
//   pieces only merge into full lines inside L2.
// XCD swizzle: batch b only gets wg ids with id%8 == b%8.
__global__ __launch_bounds__(256) void gather4_k(const float* __restrict__ x,
                                                 const int* __restrict__ offsets,
                                                 const int* __restrict__ list,
                                                 float* __restrict__ out) {
    int lin  = blockIdx.x;
    int xcd  = lin & (NXCD - 1);
    int rest = lin >> 3;                 // (b/8)*NBLK_G + t
    int t    = rest % NBLK_G;
    int b    = (rest / NBLK_G) * NXCD + xcd;

    int g = t * 256 + threadIdx.x;       // group of 4 vertices
    if (g >= NGRP) return;
    int v0 = g * 4;

    i32x4 ov = *(const i32x4*)(offsets + v0);   // 16B-aligned (v0 % 4 == 0)
    int o0 = ov.x, o1 = ov.y, o2 = ov.z, o3 = ov.w;
    int o4 = offsets[v0 + 4];

    const float* xb = x + (size_t)b * (NSEL_C * 3);

    float f00 = 0.f, f01 = 0.f, f02 = 0.f;
    float f10 = 0.f, f11 = 0.f, f12 = 0.f;
    float f20 = 0.f, f21 = 0.f, f22 = 0.f;
    float f30 = 0.f, f31 = 0.f, f32 = 0.f;

    #pragma unroll 2
    for (int k = o0; k < o4; ++k) {
        int eo  = list[k];                          // 3*j
        int eoc = eo > (3 * NSEL_C - 4) ? (3 * NSEL_C - 4) : eo;
        f32x4_u pv = *(const f32x4_u*)(xb + eoc);   // one dwordx4
        bool sh = (eoc != eo);                      // only the global last row
        float p0 = sh ? pv.y : pv.x;
        float p1 = sh ? pv.z : pv.y;
        float p2 = sh ? pv.w : pv.z;
        bool s1 = (k >= o1), s2 = (k >= o2), s3 = (k >= o3);
        bool i0 = !s1;
        bool i1 = s1 && !s2;
        bool i2 = s2 && !s3;
        bool i3 = s3;
        f00 += i0 ? p0 : 0.f;  f01 += i0 ? p1 : 0.f;  f02 += i0 ? p2 : 0.f;
        f10 += i1 ? p0 : 0.f;  f11 += i1 ? p1 : 0.f;  f12 += i1 ? p2 : 0.f;
        f20 += i2 ? p0 : 0.f;  f21 += i2 ? p1 : 0.f;  f22 += i2 ? p2 : 0.f;
        f30 += i3 ? p0 : 0.f;  f31 += i3 ? p1 : 0.f;  f32 += i3 ? p2 : 0.f;
    }

    size_t ob = ((size_t)b * NV_C + v0) * 3;   // 48B multiple -> 16B aligned
    f32x4 s0v = {f00, f01, f02, f10};
    f32x4 s1v = {f11, f12, f20, f21};
    f32x4 s2v = {f22, f30, f31, f32};
    *(f32x4*)(out + ob)     = s0v;
    *(f32x4*)(out + ob + 4) = s1v;
    *(f32x4*)(out + ob + 8) = s2v;
}

// ---------------- fallback (if ws too small): memset + atomic scatter ----------------
__global__ __launch_bounds__(256) void scatter_atomic_k(const float* __restrict__ x,
                                                        const int* __restrict__ vs,
                                                        float* __restrict__ out) {
    int j = blockIdx.x * blockDim.x + threadIdx.x;
    int b = blockIdx.y;
    if (j < NSEL_C) {
        int v = vs[j];
        const float* p = x + ((size_t)b * NSEL_C + j) * 3;
        float* q = out + ((size_t)b * NV_C + v) * 3;
        atomicAdd(q + 0, p[0]);
        atomicAdd(q + 1, p[1]);
        atomicAdd(q + 2, p[2]);
    }
}

extern "C" void kernel_launch(void* const* d_in, const int* in_sizes, int n_in,
                              void* d_out, int out_size, void* d_ws, size_t ws_size,
                              hipStream_t stream) {
    const float* x  = (const float*)d_in[0];
    const int*   vs = (const int*)d_in[1];
    float* out = (float*)d_out;

    // ws layout (ints): counts[NV] | partial[NV] | offsets[NV+1] | cursor[NV]
    //                   | blockSums[NB1] | blockOff[NB1] | list[NSEL]
    const size_t need_ints = (size_t)4 * NV_C + 1 + 2 * NB1 + NSEL_C;
    if (ws_size >= need_ints * sizeof(int)) {
        int* w        = (int*)d_ws;
        int* counts   = w;
        int* partial  = w + NV_C;
        int* offsets  = w + 2 * NV_C;          // NV_C + 1 entries
        int* cursor   = w + 3 * NV_C + 1;
        int* blockSums= w + 4 * NV_C + 1;
        int* blockOff = blockSums + NB1;
        int* list     = blockOff + NB1;

        zero_counts_k<<<(NV_C + 255) / 256, 256, 0, stream>>>(counts);
        hist_k<<<(NSEL_C + 255) / 256, 256, 0, stream>>>(vs, counts);
        scan1_k<<<NB1, SCAN_T, 0, stream>>>(counts, partial, blockSums);
        scan2_k<<<1, 64, 0, stream>>>(blockSums, blockOff);
        scan3_k<<<(NV_C + 255) / 256, 256, 0, stream>>>(partial, blockOff, offsets, cursor);
        fill_k<<<(NSEL_C + 255) / 256, 256, 0, stream>>>(vs, cursor, list);

        // 1-D swizzled grid: 256 batches x 98 group-blocks (25088 % 8 == 0)
        gather4_k<<<B_C * NBLK_G, 256, 0, stream>>>(x, offsets, list, out);
    } else {
        hipMemsetAsync(d_out, 0, (size_t)out_size * sizeof(float), stream);
        dim3 grid((NSEL_C + 255) / 256, B_C);
        scatter_atomic_k<<<grid, 256, 0, stream>>>(x, vs, out);
    }
}

// Round 5
// 214.342 us; speedup vs baseline: 1.0498x; 1.0498x over previous
//
#include <hip/hip_runtime.h>

// Problem constants (from reference): B=256, NSEL=60000, NVERTS=100000, F=3
#define B_C     256
#define NSEL_C  60000
#define NV_C    100000
#define SCAN_T  1024
#define NB1     ((NV_C + SCAN_T - 1) / SCAN_T)   // 98 scan blocks
#define NGRP    (NV_C / 4)                       // 25000 groups of 4 vertices
#define NBLK_G  ((NGRP + 255) / 256)             // 98 group-blocks per batch
#define NXCD    8
#define CAP     1536                             // staged CSR rows per block (LDS)

typedef float f32x4 __attribute__((ext_vector_type(4)));
typedef int   i32x4 __attribute__((ext_vector_type(4)));

// ---------------- CSR build ----------------

__global__ void zero_counts_k(int* __restrict__ counts) {
    int i = blockIdx.x * blockDim.x + threadIdx.x;
    if (i < NV_C) counts[i] = 0;
}

__global__ void hist_k(const int* __restrict__ vs, int* __restrict__ counts) {
    int j = blockIdx.x * blockDim.x + threadIdx.x;
    if (j < NSEL_C) atomicAdd(&counts[vs[j]], 1);
}

__global__ __launch_bounds__(SCAN_T) void scan1_k(const int* __restrict__ counts,
                                                  int* __restrict__ partial,
                                                  int* __restrict__ blockSums) {
    __shared__ int sm[SCAN_T];
    int tid = threadIdx.x;
    int i = blockIdx.x * SCAN_T + tid;
    int v = (i < NV_C) ? counts[i] : 0;
    int val = v;
    sm[tid] = val;
    __syncthreads();
    for (int off = 1; off < SCAN_T; off <<= 1) {
        int t = (tid >= off) ? sm[tid - off] : 0;
        __syncthreads();
        val += t;
        sm[tid] = val;
        __syncthreads();
    }
    if (i < NV_C) partial[i] = val - v;           // exclusive
    if (tid == SCAN_T - 1) blockSums[blockIdx.x] = val;
}

__global__ void scan2_k(const int* __restrict__ blockSums, int* __restrict__ blockOff) {
    if (blockIdx.x == 0 && threadIdx.x == 0) {
        int run = 0;
        for (int b = 0; b < NB1; ++b) { blockOff[b] = run; run += blockSums[b]; }
    }
}

__global__ void scan3_k(const int* __restrict__ partial, const int* __restrict__ blockOff,
                        int* __restrict__ offsets, int* __restrict__ cursor) {
    int i = blockIdx.x * blockDim.x + threadIdx.x;
    if (i < NV_C) {
        int o = partial[i] + blockOff[i / SCAN_T];
        offsets[i] = o;
        cursor[i]  = o;
    }
    if (i == 0) offsets[NV_C] = NSEL_C;
}

// list[] stores 3*j (float element offset into the batch slice).
__global__ void fill_k(const int* __restrict__ vs, int* __restrict__ cursor,
                       int* __restrict__ list) {
    int j = blockIdx.x * blockDim.x + threadIdx.x;
    if (j < NSEL_C) {
        int v = vs[j];
        int pos = atomicAdd(&cursor[v], 1);
        list[pos] = 3 * j;
    }
}

// ---------------- gather (the heavy kernel) ----------------
// Phase A: block cooperatively stages its CSR rows [off[vA], off[vB]) into
// LDS, 3-way unrolled (k, k+256, k+512) so 3 independent dwordx3 x-loads are
// in flight per thread — breaks the per-row serialized list->x->waitcnt chain
// that capped R2/R3/R4 at ~200 us. ds_write stride is 3 words -> 2 lanes/bank
// (free).
// Phase B: 4 vertices/thread, combined predicated loop reading rows from LDS
// (address depends only on k, no load-dependent addressing), then 3x aligned
// f32x4 coalesced plain stores.
// Fallback: if a block's row count > CAP (impossible for uniform vs, but
// input-safe), use the global-read loop for that block.
// XCD swizzle: batch b only gets wg ids with id%8 == b%8 -> per-XCD L2
// residency of the 720 KB x slice.
__global__ __launch_bounds__(256) void gather_lds_k(const float* __restrict__ x,
                                                    const int* __restrict__ offsets,
                                                    const int* __restrict__ list,
                                                    float* __restrict__ out) {
    __shared__ float sm[CAP * 3];

    int lin  = blockIdx.x;
    int xcd  = lin & (NXCD - 1);
    int rest = lin >> 3;                 // (b/8)*NBLK_G + t
    int t    = rest % NBLK_G;
    int b    = (rest / NBLK_G) * NXCD + xcd;

    int tid = threadIdx.x;
    int vA  = t * 1024;
    int vB  = min(vA + 1024, NV_C);
    int s_blk = offsets[vA];             // same addr all threads -> broadcast
    int e_blk = offsets[vB];
    int nk    = e_blk - s_blk;

    const float* xb = x + (size_t)b * (NSEL_C * 3);

    // Load this thread's segment bounds early (independent of staging).
    int g  = t * 256 + tid;              // group of 4 vertices
    int v0 = g * 4;
    int o0 = 0, o1 = 0, o2 = 0, o3 = 0, o4 = 0;
    if (g < NGRP) {
        i32x4 ov = *(const i32x4*)(offsets + v0);   // 16B-aligned
        o0 = ov.x; o1 = ov.y; o2 = ov.z; o3 = ov.w;
        o4 = offsets[v0 + 4];
    }

    if (nk <= CAP) {
        for (int k0 = s_blk + tid; k0 < e_blk; k0 += 768) {
            int k1 = k0 + 256, k2 = k0 + 512;
            bool h1 = (k1 < e_blk), h2 = (k2 < e_blk);
            int e0 = list[k0];
            int e1 = h1 ? list[k1] : e0;
            int e2 = h2 ? list[k2] : e0;
            float a0 = xb[e0], a1 = xb[e0 + 1], a2 = xb[e0 + 2];
            float b0 = xb[e1], b1 = xb[e1 + 1], b2 = xb[e1 + 2];
            float c0 = xb[e2], c1 = xb[e2 + 1], c2 = xb[e2 + 2];
            int p = (k0 - s_blk) * 3;
            sm[p] = a0; sm[p + 1] = a1; sm[p + 2] = a2;
            if (h1) { int q = p + 768;  sm[q] = b0; sm[q + 1] = b1; sm[q + 2] = b2; }
            if (h2) { int q = p + 1536; sm[q] = c0; sm[q + 1] = c1; sm[q + 2] = c2; }
        }
    }
    __syncthreads();

    if (g >= NGRP) return;

    float f00 = 0.f, f01 = 0.f, f02 = 0.f;
    float f10 = 0.f, f11 = 0.f, f12 = 0.f;
    float f20 = 0.f, f21 = 0.f, f22 = 0.f;
    float f30 = 0.f, f31 = 0.f, f32 = 0.f;

    if (nk <= CAP) {
        for (int k = o0; k < o4; ++k) {
            int p = (k - s_blk) * 3;
            float p0 = sm[p], p1 = sm[p + 1], p2 = sm[p + 2];
            bool s1 = (k >= o1), s2 = (k >= o2), s3 = (k >= o3);
            bool i0 = !s1, i1 = s1 && !s2, i2 = s2 && !s3, i3 = s3;
            f00 += i0 ? p0 : 0.f;  f01 += i0 ? p1 : 0.f;  f02 += i0 ? p2 : 0.f;
            f10 += i1 ? p0 : 0.f;  f11 += i1 ? p1 : 0.f;  f12 += i1 ? p2 : 0.f;
            f20 += i2 ? p0 : 0.f;  f21 += i2 ? p1 : 0.f;  f22 += i2 ? p2 : 0.f;
            f30 += i3 ? p0 : 0.f;  f31 += i3 ? p1 : 0.f;  f32 += i3 ? p2 : 0.f;
        }
    } else {
        for (int k = o0; k < o4; ++k) {
            int eo = list[k];
            float p0 = xb[eo], p1 = xb[eo + 1], p2 = xb[eo + 2];
            bool s1 = (k >= o1), s2 = (k >= o2), s3 = (k >= o3);
            bool i0 = !s1, i1 = s1 && !s2, i2 = s2 && !s3, i3 = s3;
            f00 += i0 ? p0 : 0.f;  f01 += i0 ? p1 : 0.f;  f02 += i0 ? p2 : 0.f;
            f10 += i1 ? p0 : 0.f;  f11 += i1 ? p1 : 0.f;  f12 += i1 ? p2 : 0.f;
            f20 += i2 ? p0 : 0.f;  f21 += i2 ? p1 : 0.f;  f22 += i2 ? p2 : 0.f;
            f30 += i3 ? p0 : 0.f;  f31 += i3 ? p1 : 0.f;  f32 += i3 ? p2 : 0.f;
        }
    }

    size_t ob = ((size_t)b * NV_C + v0) * 3;   // 48B multiple -> 16B aligned
    f32x4 s0v = {f00, f01, f02, f10};
    f32x4 s1v = {f11, f12, f20, f21};
    f32x4 s2v = {f22, f30, f31, f32};
    *(f32x4*)(out + ob)     = s0v;
    *(f32x4*)(out + ob + 4) = s1v;
    *(f32x4*)(out + ob + 8) = s2v;
}

// ---------------- fallback (if ws too small): memset + atomic scatter ----------------
__global__ __launch_bounds__(256) void scatter_atomic_k(const float* __restrict__ x,
                                                        const int* __restrict__ vs,
                                                        float* __restrict__ out) {
    int j = blockIdx.x * blockDim.x + threadIdx.x;
    int b = blockIdx.y;
    if (j < NSEL_C) {
        int v = vs[j];
        const float* p = x + ((size_t)b * NSEL_C + j) * 3;
        float* q = out + ((size_t)b * NV_C + v) * 3;
        atomicAdd(q + 0, p[0]);
        atomicAdd(q + 1, p[1]);
        atomicAdd(q + 2, p[2]);
    }
}

extern "C" void kernel_launch(void* const* d_in, const int* in_sizes, int n_in,
                              void* d_out, int out_size, void* d_ws, size_t ws_size,
                              hipStream_t stream) {
    const float* x  = (const float*)d_in[0];
    const int*   vs = (const int*)d_in[1];
    float* out = (float*)d_out;

    // ws layout (ints): counts[NV] | partial[NV] | offsets[NV+1] | cursor[NV]
    //                   | blockSums[NB1] | blockOff[NB1] | list[NSEL]
    const size_t need_ints = (size_t)4 * NV_C + 1 + 2 * NB1 + NSEL_C;
    if (ws_size >= need_ints * sizeof(int)) {
        int* w        = (int*)d_ws;
        int* counts   = w;
        int* partial  = w + NV_C;
        int* offsets  = w + 2 * NV_C;          // NV_C + 1 entries
        int* cursor   = w + 3 * NV_C + 1;
        int* blockSums= w + 4 * NV_C + 1;
        int* blockOff = blockSums + NB1;
        int* list     = blockOff + NB1;

        zero_counts_k<<<(NV_C + 255) / 256, 256, 0, stream>>>(counts);
        hist_k<<<(NSEL_C + 255) / 256, 256, 0, stream>>>(vs, counts);
        scan1_k<<<NB1, SCAN_T, 0, stream>>>(counts, partial, blockSums);
        scan2_k<<<1, 64, 0, stream>>>(blockSums, blockOff);
        scan3_k<<<(NV_C + 255) / 256, 256, 0, stream>>>(partial, blockOff, offsets, cursor);
        fill_k<<<(NSEL_C + 255) / 256, 256, 0, stream>>>(vs, cursor, list);

        // 1-D swizzled grid: 256 batches x 98 group-blocks (25088 % 8 == 0)
        gather_lds_k<<<B_C * NBLK_G, 256, 0, stream>>>(x, offsets, list, out);
    } else {
        hipMemsetAsync(d_out, 0, (size_t)out_size * sizeof(float), stream);
        dim3 grid((NSEL_C + 255) / 256, B_C);
        scatter_atomic_k<<<grid, 256, 0, stream>>>(x, vs, out);
    }
}